// Round 1
// baseline (731.142 us; speedup 1.0000x reference)
//
#include <hip/hip_runtime.h>

// VirtualParameter sparse superposition:
//   out[b, io] = sum_k probs[b,k] * param[io*64 + sel[b,k]]
// B=128, K=4, io in [0, 1024*1024), BANKS=64 (innermost dim of param).
//
// Memory-bound: 256 MiB param read (exactly once) + 512 MiB out write.
// Strategy: per block, stage a 256-io x 64-bank param tile (64 KB) into LDS
// transposed + XOR-swizzled, then loop over all 128 b's reusing the tile.

#define B_CTX 128
#define DIO   (1024 * 1024)   // D_IN * D_OUT
#define BANKS 64
#define TILE  256             // io positions per block == threads per block

__global__ __launch_bounds__(TILE, 2)
void vp_sparse_kernel(const int*   __restrict__ sel,    // (128,4) int32
                      const float* __restrict__ probs,  // (128,4) f32
                      const float* __restrict__ param,  // (DIO, 64) f32
                      float*       __restrict__ out)    // (128, DIO) f32
{
    // Layout: sm[n*TILE + (r ^ (n&31))], n=bank, r=local io.
    // Bijective per row (XOR with const <32 stays in [0,256)).
    // Read phase bank = (t ^ sel) & 31 -> 2-way over wave64 (free).
    // Write phase bank = (io_local ^ n) & 31 -> 2-way (free).
    __shared__ float sm[BANKS * TILE];  // 64 KB

    const int t = threadIdx.x;
    const size_t io_base = (size_t)blockIdx.x * TILE;

    // ---- Stage: global (io-major, bank-minor) -> LDS (bank-major) ----
    // Tile region = TILE*BANKS floats = 4096 float4; f4 = i*256 + t is
    // fully coalesced (1 KB per wave-instruction).
    const float4* gp = (const float4*)(param + io_base * BANKS);
    #pragma unroll
    for (int i = 0; i < 16; ++i) {
        const int f4 = i * TILE + t;
        const float4 v = gp[f4];
        const int r = f4 >> 4;          // local io
        const int n = (f4 & 15) * 4;    // bank base (multiple of 4)
        sm[(n + 0) * TILE + (r ^ ((n + 0) & 31))] = v.x;
        sm[(n + 1) * TILE + (r ^ ((n + 1) & 31))] = v.y;
        sm[(n + 2) * TILE + (r ^ ((n + 2) & 31))] = v.z;
        sm[(n + 3) * TILE + (r ^ ((n + 3) & 31))] = v.w;
    }
    __syncthreads();

    // ---- Sweep all 128 selection contexts over the staged tile ----
    const int4*   sel4 = (const int4*)sel;     // wave-uniform -> s_load
    const float4* pr4  = (const float4*)probs; // wave-uniform -> s_load
    float* op = out + io_base + t;

    #pragma unroll 4
    for (int b = 0; b < B_CTX; ++b) {
        const int4   s = sel4[b];
        const float4 p = pr4[b];
        float acc;
        acc = p.x * sm[s.x * TILE + (t ^ (s.x & 31))];
        acc = fmaf(p.y, sm[s.y * TILE + (t ^ (s.y & 31))], acc);
        acc = fmaf(p.z, sm[s.z * TILE + (t ^ (s.z & 31))], acc);
        acc = fmaf(p.w, sm[s.w * TILE + (t ^ (s.w & 31))], acc);
        op[(size_t)b * DIO] = acc;   // 256 B contiguous per wave store
    }
}

extern "C" void kernel_launch(void* const* d_in, const int* in_sizes, int n_in,
                              void* d_out, int out_size, void* d_ws, size_t ws_size,
                              hipStream_t stream) {
    const int*   sel   = (const int*)d_in[0];
    const float* probs = (const float*)d_in[1];
    const float* param = (const float*)d_in[2];
    float*       out   = (float*)d_out;

    dim3 grid(DIO / TILE);
    dim3 block(TILE);
    hipLaunchKernelGGL(vp_sparse_kernel, grid, block, 0, stream,
                       sel, probs, param, out);
}